// Round 4
// baseline (345.607 us; speedup 1.0000x reference)
//
#include <hip/hip_runtime.h>
#include <cstdint>

// EdgeMLP R4: LDS-streamed W1 fragments + 32x32x16 MFMA, 32 edges/wave-iter,
// 3 waves/SIMD occupancy, all-MFMA layer2 via register relabeling.
// ws layout: [hb: nNodes*64 bf16][W1f 16384 bf16][W2f 4096 bf16][b1f 128 f32]

constexpr int EMB = 64;
constexpr int HID = 128;

typedef short s16x8 __attribute__((ext_vector_type(8)));
typedef float f32x16 __attribute__((ext_vector_type(16)));

__device__ __forceinline__ unsigned short f2bf(float x) {
    unsigned u = __float_as_uint(x);
    u = (u + 0x7fffu + ((u >> 16) & 1u)) >> 16;   // RNE
    return (unsigned short)u;
}

// ---- prep 1: h fp32 -> bf16 ----
__global__ void conv_h_kernel(const float* __restrict__ h,
                              unsigned short* __restrict__ hb, int n8) {
    const int i = blockIdx.x * blockDim.x + threadIdx.x;
    if (i >= n8) return;
    const float* p = h + (size_t)i * 8;
    float4 a = *reinterpret_cast<const float4*>(p);
    float4 b = *reinterpret_cast<const float4*>(p + 4);
    unsigned short r[8];
    r[0] = f2bf(a.x); r[1] = f2bf(a.y); r[2] = f2bf(a.z); r[3] = f2bf(a.w);
    r[4] = f2bf(b.x); r[5] = f2bf(b.y); r[6] = f2bf(b.z); r[7] = f2bf(b.w);
    *reinterpret_cast<uint4*>(hb + (size_t)i * 8) = *reinterpret_cast<const uint4*>(r);
}

// ---- prep 2: fragment-ordered weight/bias tables ----
// W1f[i], i = ((mt*8+ks)*64+lane)*8+j : bf16(W1[k][h]), k=ks*16+(lane>>5)*8+j,
//                                       h=mt*32+(lane&31)
// W2f[q], q = (ks2*64+lane)*8+j : lane m=lane&31, hi=lane>>5;
//   hidden = (ks2>>1)*32 + (j&3) + 8*((ks2&1)*2+(j>>2)) + 4*hi;
//   val = (m<2) ? bf16(W2[hidden*2+m]) : 0
// b1f[q] (f32), q = hi*64+mt*16+r : b1[mt*32 + (r&3)+8*(r>>2)+4*hi]
__global__ void pack_tables(const float* __restrict__ W1,
                            const float* __restrict__ b1,
                            const float* __restrict__ W2,
                            unsigned short* __restrict__ tab) {
    const int i = blockIdx.x * blockDim.x + threadIdx.x;
    if (i < 16384) {
        const int j = i & 7, lane = (i >> 3) & 63, ks = (i >> 9) & 7, mt = i >> 12;
        const int k = ks * 16 + (lane >> 5) * 8 + j;
        const int h = mt * 32 + (lane & 31);
        tab[i] = f2bf(W1[(size_t)k * HID + h]);
    } else if (i < 16384 + 4096) {
        const int q = i - 16384;
        const int j = q & 7, lane = (q >> 3) & 63, ks2 = q >> 9;
        const int m = lane & 31, hi = (lane >> 5) & 1;
        const int hidden = (ks2 >> 1) * 32 + (j & 3) + 8 * ((ks2 & 1) * 2 + (j >> 2)) + 4 * hi;
        tab[i] = (m < 2) ? f2bf(W2[hidden * 2 + m]) : (unsigned short)0;
    } else if (i < 16384 + 4096 + 128) {
        const int q = i - 16384 - 4096;
        const int hi = q >> 6, mt = (q >> 4) & 3, r = q & 15;
        float* btab = reinterpret_cast<float*>(tab + 16384 + 4096);
        btab[q] = b1[mt * 32 + (r & 3) + 8 * (r >> 2) + 4 * hi];
    }
}

// ---- main ----
__global__ __launch_bounds__(256, 3)
void edge_mlp_lds(const unsigned short* __restrict__ hb,
                  const unsigned short* __restrict__ tab,
                  const int* __restrict__ eidx,
                  const float* __restrict__ b2,
                  float* __restrict__ out, int E, int nIters)
{
    __shared__ uint4 smem[2592];   // 41472 B: W1f[0,32768) W2f[32768,40960) b1f[40960,41472)
    {
        const uint4* wq = reinterpret_cast<const uint4*>(tab);
        for (int i = threadIdx.x; i < 2592; i += 256) smem[i] = wq[i];
    }
    __syncthreads();
    const char* sb = reinterpret_cast<const char*>(smem);

    const int t = threadIdx.x, wid = t >> 6, lane = t & 63;
    const int e32 = lane & 31, hi = lane >> 5;

    const float b20 = (hi == 0) ? b2[0] : 0.f;
    const float b21 = (hi == 0) ? b2[1] : 0.f;

    const int stride = gridDim.x * 4;
    for (int iter = blockIdx.x * 4 + wid; iter < nIters; iter += stride) {
        const int e = min(iter * 32 + e32, E - 1);
        const int s = eidx[e], d = eidx[E + e];

        // gather X B-fragments: k = ks*16 + hi*8 + j  (ks<4 -> src, ks>=4 -> dst)
        const unsigned short* ps = hb + ((size_t)s << 6) + hi * 8;
        const unsigned short* pd = hb + ((size_t)d << 6) + hi * 8;
        s16x8 xf[8];
        #pragma unroll
        for (int ks = 0; ks < 4; ++ks)
            xf[ks] = *reinterpret_cast<const s16x8*>(ps + ks * 16);
        #pragma unroll
        for (int ks = 0; ks < 4; ++ks)
            xf[ks + 4] = *reinterpret_cast<const s16x8*>(pd + ks * 16);

        // layer-1 acc init = b1 (broadcast LDS reads, C-layout table)
        f32x16 acc[4];
        #pragma unroll
        for (int mt = 0; mt < 4; ++mt) {
            #pragma unroll
            for (int q = 0; q < 4; ++q) {
                const float4 bq = *reinterpret_cast<const float4*>(
                    sb + 40960 + (hi * 64 + mt * 16 + q * 4) * 4);
                acc[mt][q * 4 + 0] = bq.x; acc[mt][q * 4 + 1] = bq.y;
                acc[mt][q * 4 + 2] = bq.z; acc[mt][q * 4 + 3] = bq.w;
            }
        }

        // layer 1: C = W1^T (A, from LDS) x X (B, gathered); C col = edge
        #pragma unroll
        for (int ks = 0; ks < 8; ++ks) {
            #pragma unroll
            for (int mt = 0; mt < 4; ++mt) {
                const s16x8 wa = *reinterpret_cast<const s16x8*>(
                    sb + ((mt * 8 + ks) * 64 + lane) * 16);
                acc[mt] = __builtin_amdgcn_mfma_f32_32x32x16_bf16(wa, xf[ks], acc[mt], 0, 0, 0);
            }
        }

        // relu + relabel C(mt, r=j+(ks2&1)*8) -> layer-2 B-fragment p[ks2]
        s16x8 p[8];
        #pragma unroll
        for (int ks2 = 0; ks2 < 8; ++ks2) {
            #pragma unroll
            for (int j = 0; j < 8; ++j)
                p[ks2][j] = (short)f2bf(fmaxf(acc[ks2 >> 1][j + (ks2 & 1) * 8], 0.f));
        }

        // layer 2: 8 MFMAs with permuted-W2 A-fragments from LDS
        f32x16 acc2;
        acc2[0] = b20; acc2[1] = b21;
        #pragma unroll
        for (int q = 2; q < 16; ++q) acc2[q] = 0.f;
        #pragma unroll
        for (int ks2 = 0; ks2 < 8; ++ks2) {
            const s16x8 w2a = *reinterpret_cast<const s16x8*>(
                sb + 32768 + (ks2 * 64 + lane) * 16);
            acc2 = __builtin_amdgcn_mfma_f32_32x32x16_bf16(w2a, p[ks2], acc2, 0, 0, 0);
        }

        // C2 rows 0,1 live in hi==0 lanes, col = edge
        const int eo = iter * 32 + e32;
        if (hi == 0 && eo < E)
            *reinterpret_cast<float2*>(out + (size_t)eo * 2) = make_float2(acc2[0], acc2[1]);
    }
}

// ---- fallback (only if ws too small; slow but correct) ----
__global__ void edge_mlp_naive(const float* __restrict__ h, const int* __restrict__ eidx,
                               const float* __restrict__ W1, const float* __restrict__ b1,
                               const float* __restrict__ W2, const float* __restrict__ b2,
                               float* __restrict__ out, int E) {
    const int e = blockIdx.x * 256 + threadIdx.x;
    if (e >= E) return;
    const float* hs = h + (size_t)eidx[e] * EMB;
    const float* hd = h + (size_t)eidx[E + e] * EMB;
    float o0 = b2[0], o1 = b2[1];
    for (int j = 0; j < HID; ++j) {
        float a = b1[j];
        for (int k = 0; k < EMB; ++k)
            a += hs[k] * W1[(size_t)k * HID + j] + hd[k] * W1[(size_t)(k + EMB) * HID + j];
        a = fmaxf(a, 0.f);
        o0 = fmaf(a, W2[j * 2 + 0], o0);
        o1 = fmaf(a, W2[j * 2 + 1], o1);
    }
    out[(size_t)e * 2 + 0] = o0;
    out[(size_t)e * 2 + 1] = o1;
}

extern "C" void kernel_launch(void* const* d_in, const int* in_sizes, int n_in,
                              void* d_out, int out_size, void* d_ws, size_t ws_size,
                              hipStream_t stream)
{
    const float* h  = (const float*)d_in[0];
    const int*   ei = (const int*)d_in[1];
    const float* W1 = (const float*)d_in[2];
    const float* b1 = (const float*)d_in[3];
    const float* W2 = (const float*)d_in[4];
    const float* b2 = (const float*)d_in[5];
    float* out = (float*)d_out;

    const int nNodes = in_sizes[0] / EMB;
    const int E      = in_sizes[1] / 2;
    const int nIters = (E + 31) / 32;

    const size_t hbElems = (size_t)nNodes * EMB;
    const size_t need    = hbElems * 2 + (16384 + 4096) * 2 + 128 * 4;

    if (ws_size >= need) {
        unsigned short* hb  = (unsigned short*)d_ws;
        unsigned short* tab = hb + hbElems;
        const int n8 = (int)(hbElems / 8);
        hipLaunchKernelGGL(conv_h_kernel, dim3((n8 + 255) / 256), dim3(256), 0, stream,
                           h, hb, n8);
        hipLaunchKernelGGL(pack_tables, dim3(81), dim3(256), 0, stream, W1, b1, W2, tab);
        hipLaunchKernelGGL(edge_mlp_lds, dim3(768), dim3(256), 0, stream,
                           hb, tab, ei, b2, out, E, nIters);
    } else {
        hipLaunchKernelGGL(edge_mlp_naive, dim3((E + 255) / 256), dim3(256), 0, stream,
                           h, ei, W1, b1, W2, b2, out, E);
    }
}

// Round 5
// 304.834 us; speedup vs baseline: 1.1338x; 1.1338x over previous
//
#include <hip/hip_runtime.h>
#include <cstdint>

// EdgeMLP R5: 16x16x32 MFMA (R3-validated layouts), W1 frags in LDS (32 KB),
// 32-edge tiles (2 sub-tiles share each W1 ds_read), 3 waves/SIMD, persistent.
// ws: [hb: nNodes*64 bf16][w1tab: 16384 bf16]

constexpr int EMB = 64;
constexpr int HID = 128;

typedef short s16x8 __attribute__((ext_vector_type(8)));
typedef float f32x4 __attribute__((ext_vector_type(4)));

__device__ __forceinline__ unsigned short f2bf(float x) {
    unsigned u = __float_as_uint(x);
    u = (u + 0x7fffu + ((u >> 16) & 1u)) >> 16;   // RNE
    return (unsigned short)u;
}

// ---- prep 1: h fp32 -> bf16 ----
__global__ void conv_h_kernel(const float* __restrict__ h,
                              unsigned short* __restrict__ hb, int n8) {
    const int i = blockIdx.x * blockDim.x + threadIdx.x;
    if (i >= n8) return;
    const float* p = h + (size_t)i * 8;
    float4 a = *reinterpret_cast<const float4*>(p);
    float4 b = *reinterpret_cast<const float4*>(p + 4);
    unsigned short r[8];
    r[0] = f2bf(a.x); r[1] = f2bf(a.y); r[2] = f2bf(a.z); r[3] = f2bf(a.w);
    r[4] = f2bf(b.x); r[5] = f2bf(b.y); r[6] = f2bf(b.z); r[7] = f2bf(b.w);
    *reinterpret_cast<uint4*>(hb + (size_t)i * 8) = *reinterpret_cast<const uint4*>(r);
}

// ---- prep 2: W1 -> 16x16 A-fragment order ----
// i = ((nt*4+ks)*64+lane)*8+j : value bf16(W1[k][n]), k=ks*32+(lane>>4)*8+j,
//                               n=nt*16+(lane&15)
__global__ void pack_w1(const float* __restrict__ W1,
                        unsigned short* __restrict__ tab) {
    const int i = blockIdx.x * blockDim.x + threadIdx.x;
    if (i >= 16384) return;
    const int j = i & 7, lane = (i >> 3) & 63, ks = (i >> 9) & 3, nt = i >> 11;
    const int k = ks * 32 + (lane >> 4) * 8 + j;
    const int n = nt * 16 + (lane & 15);
    tab[i] = f2bf(W1[(size_t)k * HID + n]);
}

// ---- main ----
__global__ __launch_bounds__(256, 3)
void edge_mlp_r5(const unsigned short* __restrict__ hb,
                 const unsigned short* __restrict__ w1tab,
                 const int* __restrict__ eidx,
                 const float* __restrict__ b1,
                 const float* __restrict__ W2, const float* __restrict__ b2,
                 float* __restrict__ out, int E, int nTiles32)
{
    __shared__ uint4 w1s[2048];   // 32 KB of A-fragments
    {
        const uint4* src = reinterpret_cast<const uint4*>(w1tab);
        #pragma unroll
        for (int r = 0; r < 8; ++r) w1s[r * 256 + threadIdx.x] = src[r * 256 + threadIdx.x];
    }
    __syncthreads();

    const int t = threadIdx.x, wid = t >> 6, lane = t & 63;
    const int tc = lane & 15, bq = lane >> 4;
    const s16x8* wf = reinterpret_cast<const s16x8*>(w1s) + lane;  // + (nt*4+ks)*64

    // Layer-2 permuted W2 A-fragments (R3-validated formula)
    s16x8 w2f[4];
    #pragma unroll
    for (int ks = 0; ks < 4; ++ks) {
        s16x8 f;
        #pragma unroll
        for (int j = 0; j < 8; ++j) {
            const int mt = ks * 2 + (j >> 2), r = j & 3;
            f[j] = (tc < 2) ? (short)f2bf(W2[(mt * 16 + bq * 4 + r) * 2 + tc]) : (short)0;
        }
        w2f[ks] = f;
    }
    // b1 in C layout, packed bf16 (R3-validated)
    uint2 b1p[8];
    #pragma unroll
    for (int mt = 0; mt < 8; ++mt) {
        const int u0 = mt * 16 + bq * 4;
        b1p[mt].x = (unsigned)f2bf(b1[u0 + 0]) | ((unsigned)f2bf(b1[u0 + 1]) << 16);
        b1p[mt].y = (unsigned)f2bf(b1[u0 + 2]) | ((unsigned)f2bf(b1[u0 + 3]) << 16);
    }
    const float a20 = (bq == 0) ? b2[0] : 0.f;
    const float a21 = (bq == 0) ? b2[1] : 0.f;

    const int stride = gridDim.x * 4;
    int tile = blockIdx.x * 4 + wid;
    if (tile >= nTiles32) return;

    auto LOADIDX = [&](int tl, int& sA, int& dA, int& sB, int& dB) {
        const int base = tl * 32;
        const int eA = min(base + tc, E - 1);
        const int eB = min(base + 16 + tc, E - 1);
        sA = eidx[eA]; dA = eidx[E + eA];
        sB = eidx[eB]; dB = eidx[E + eB];
    };
    auto GATHER = [&](int s, int d, s16x8 (&xf)[4]) {
        const s16x8* ps = reinterpret_cast<const s16x8*>(hb + (size_t)s * EMB + bq * 8);
        const s16x8* pd = reinterpret_cast<const s16x8*>(hb + (size_t)d * EMB + bq * 8);
        xf[0] = ps[0]; xf[1] = ps[4];
        xf[2] = pd[0]; xf[3] = pd[4];
    };

    int sA, dA, sB, dB;
    LOADIDX(tile, sA, dA, sB, dB);
    s16x8 xfA[4], xfB[4];
    GATHER(sA, dA, xfA);
    GATHER(sB, dB, xfB);

    while (true) {
        const int nxt = tile + stride;
        const bool hasNext = (nxt < nTiles32);
        if (hasNext) LOADIDX(nxt, sA, dA, sB, dB);   // idx prefetch (hidden under layer1)

        // ---- layer 1, both sub-tiles share each W1 fragment read ----
        f32x4 accA[8], accB[8];
        #pragma unroll
        for (int mt = 0; mt < 8; ++mt) {
            f32x4 ini;
            ini[0] = __uint_as_float(b1p[mt].x << 16);
            ini[1] = __uint_as_float(b1p[mt].x & 0xffff0000u);
            ini[2] = __uint_as_float(b1p[mt].y << 16);
            ini[3] = __uint_as_float(b1p[mt].y & 0xffff0000u);
            accA[mt] = ini; accB[mt] = ini;
        }
        #pragma unroll
        for (int ks = 0; ks < 4; ++ks) {
            #pragma unroll
            for (int nt = 0; nt < 8; ++nt) {
                const s16x8 w = wf[(nt * 4 + ks) * 64];
                accA[nt] = __builtin_amdgcn_mfma_f32_16x16x32_bf16(w, xfA[ks], accA[nt], 0, 0, 0);
                accB[nt] = __builtin_amdgcn_mfma_f32_16x16x32_bf16(w, xfB[ks], accB[nt], 0, 0, 0);
            }
        }

        // ---- issue next tile's gathers now (xf dead; hides under epilogue) ----
        if (hasNext) { GATHER(sA, dA, xfA); GATHER(sB, dB, xfB); }

        // ---- layer 2 + store, per sub-tile (R3-validated relabel) ----
        #pragma unroll
        for (int half = 0; half < 2; ++half) {
            f32x4* acc = half ? accB : accA;
            s16x8 p[4];
            #pragma unroll
            for (int ks2 = 0; ks2 < 4; ++ks2)
                #pragma unroll
                for (int j = 0; j < 8; ++j) {
                    const int mt = ks2 * 2 + (j >> 2), r = j & 3;
                    p[ks2][j] = (short)f2bf(fmaxf(acc[mt][r], 0.f));
                }
            f32x4 o = {a20, a21, 0.f, 0.f};
            #pragma unroll
            for (int ks2 = 0; ks2 < 4; ++ks2)
                o = __builtin_amdgcn_mfma_f32_16x16x32_bf16(w2f[ks2], p[ks2], o, 0, 0, 0);
            if (lane < 16) {
                const int eo = tile * 32 + half * 16 + lane;
                if (eo < E)
                    *reinterpret_cast<float2*>(out + (size_t)eo * 2) = make_float2(o[0], o[1]);
            }
        }

        if (!hasNext) break;
        tile = nxt;
    }
}

// ---- fallback (ws too small; correct but slow) ----
__global__ void edge_mlp_naive(const float* __restrict__ h, const int* __restrict__ eidx,
                               const float* __restrict__ W1, const float* __restrict__ b1,
                               const float* __restrict__ W2, const float* __restrict__ b2,
                               float* __restrict__ out, int E) {
    const int e = blockIdx.x * 256 + threadIdx.x;
    if (e >= E) return;
    const float* hs = h + (size_t)eidx[e] * EMB;
    const float* hd = h + (size_t)eidx[E + e] * EMB;
    float o0 = b2[0], o1 = b2[1];
    for (int j = 0; j < HID; ++j) {
        float a = b1[j];
        for (int k = 0; k < EMB; ++k)
            a += hs[k] * W1[(size_t)k * HID + j] + hd[k] * W1[(size_t)(k + EMB) * HID + j];
        a = fmaxf(a, 0.f);
        o0 = fmaf(a, W2[j * 2 + 0], o0);
        o1 = fmaf(a, W2[j * 2 + 1], o1);
    }
    out[(size_t)e * 2 + 0] = o0;
    out[(size_t)e * 2 + 1] = o1;
}

extern "C" void kernel_launch(void* const* d_in, const int* in_sizes, int n_in,
                              void* d_out, int out_size, void* d_ws, size_t ws_size,
                              hipStream_t stream)
{
    const float* h  = (const float*)d_in[0];
    const int*   ei = (const int*)d_in[1];
    const float* W1 = (const float*)d_in[2];
    const float* b1 = (const float*)d_in[3];
    const float* W2 = (const float*)d_in[4];
    const float* b2 = (const float*)d_in[5];
    float* out = (float*)d_out;

    const int nNodes   = in_sizes[0] / EMB;
    const int E        = in_sizes[1] / 2;
    const int nTiles32 = (E + 31) / 32;

    const size_t hbElems = (size_t)nNodes * EMB;
    const size_t need    = hbElems * 2 + 16384 * 2;

    if (ws_size >= need) {
        unsigned short* hb  = (unsigned short*)d_ws;
        unsigned short* tab = hb + hbElems;
        const int n8 = (int)(hbElems / 8);
        hipLaunchKernelGGL(conv_h_kernel, dim3((n8 + 255) / 256), dim3(256), 0, stream,
                           h, hb, n8);
        hipLaunchKernelGGL(pack_w1, dim3(64), dim3(256), 0, stream, W1, tab);
        hipLaunchKernelGGL(edge_mlp_r5, dim3(768), dim3(256), 0, stream,
                           hb, tab, ei, b1, W2, b2, out, E, nTiles32);
    } else {
        hipLaunchKernelGGL(edge_mlp_naive, dim3((E + 255) / 256), dim3(256), 0, stream,
                           h, ei, W1, b1, W2, b2, out, E);
    }
}

// Round 6
// 96.027 us; speedup vs baseline: 3.5991x; 3.1745x over previous
//
#include <hip/hip_runtime.h>
#include <cstdint>

// EdgeMLP R6: 16x16x32 MFMA (R3-validated layouts), W1 frags in LDS (32 KB),
// 16-edge tiles, depth-2 gather pipeline, VGPR budget ~110 (no spills),
// grid 1024 persistent (4 blocks/CU), all-MFMA layer2.
// ws: [hb: nNodes*64 bf16][w1tab: 16384 bf16]

constexpr int EMB = 64;
constexpr int HID = 128;

typedef short s16x8 __attribute__((ext_vector_type(8)));
typedef float f32x4 __attribute__((ext_vector_type(4)));

__device__ __forceinline__ unsigned short f2bf(float x) {
    unsigned u = __float_as_uint(x);
    u = (u + 0x7fffu + ((u >> 16) & 1u)) >> 16;   // RNE
    return (unsigned short)u;
}

// ---- prep 1: h fp32 -> bf16 ----
__global__ void conv_h_kernel(const float* __restrict__ h,
                              unsigned short* __restrict__ hb, int n8) {
    const int i = blockIdx.x * blockDim.x + threadIdx.x;
    if (i >= n8) return;
    const float* p = h + (size_t)i * 8;
    float4 a = *reinterpret_cast<const float4*>(p);
    float4 b = *reinterpret_cast<const float4*>(p + 4);
    unsigned short r[8];
    r[0] = f2bf(a.x); r[1] = f2bf(a.y); r[2] = f2bf(a.z); r[3] = f2bf(a.w);
    r[4] = f2bf(b.x); r[5] = f2bf(b.y); r[6] = f2bf(b.z); r[7] = f2bf(b.w);
    *reinterpret_cast<uint4*>(hb + (size_t)i * 8) = *reinterpret_cast<const uint4*>(r);
}

// ---- prep 2: W1 -> 16x16 A-fragment order ----
// i = ((nt*4+ks)*64+lane)*8+j : bf16(W1[k][n]), k=ks*32+(lane>>4)*8+j, n=nt*16+(lane&15)
__global__ void pack_w1(const float* __restrict__ W1,
                        unsigned short* __restrict__ tab) {
    const int i = blockIdx.x * blockDim.x + threadIdx.x;
    if (i >= 16384) return;
    const int j = i & 7, lane = (i >> 3) & 63, ks = (i >> 9) & 3, nt = i >> 11;
    const int k = ks * 32 + (lane >> 4) * 8 + j;
    const int n = nt * 16 + (lane & 15);
    tab[i] = f2bf(W1[(size_t)k * HID + n]);
}

// ---- main ----
__global__ __launch_bounds__(256, 2)
void edge_mlp_r6(const unsigned short* __restrict__ hb,
                 const unsigned short* __restrict__ w1tab,
                 const int* __restrict__ eidx,
                 const float* __restrict__ b1,
                 const float* __restrict__ W2, const float* __restrict__ b2,
                 float* __restrict__ out, int E, int nTiles)
{
    __shared__ uint4 w1s[2048];   // 32 KB of W1 A-fragments
    {
        const uint4* src = reinterpret_cast<const uint4*>(w1tab);
        #pragma unroll
        for (int r = 0; r < 8; ++r)
            w1s[r * 256 + threadIdx.x] = src[r * 256 + threadIdx.x];
    }
    __syncthreads();

    const int t = threadIdx.x, wid = t >> 6, lane = t & 63;
    const int tc = lane & 15, bq = lane >> 4;
    const s16x8* wf = reinterpret_cast<const s16x8*>(w1s) + lane;  // + (nt*4+ks)*64

    // Layer-2 permuted W2 A-fragments (R3-validated)
    s16x8 w2f[4];
    #pragma unroll
    for (int ks = 0; ks < 4; ++ks) {
        s16x8 f;
        #pragma unroll
        for (int j = 0; j < 8; ++j) {
            const int mt = ks * 2 + (j >> 2), r = j & 3;
            f[j] = (tc < 2) ? (short)f2bf(W2[(mt * 16 + bq * 4 + r) * 2 + tc]) : (short)0;
        }
        w2f[ks] = f;
    }
    // b1 in C layout, packed bf16 (R3-validated)
    uint2 b1p[8];
    #pragma unroll
    for (int mt = 0; mt < 8; ++mt) {
        const int u0 = mt * 16 + bq * 4;
        b1p[mt].x = (unsigned)f2bf(b1[u0 + 0]) | ((unsigned)f2bf(b1[u0 + 1]) << 16);
        b1p[mt].y = (unsigned)f2bf(b1[u0 + 2]) | ((unsigned)f2bf(b1[u0 + 3]) << 16);
    }
    const float a20 = (bq == 0) ? b2[0] : 0.f;
    const float a21 = (bq == 0) ? b2[1] : 0.f;

    const int stride = gridDim.x * 4;
    int tile = blockIdx.x * 4 + wid;
    if (tile >= nTiles) return;

    auto LOADIDX = [&](int tl, int& s, int& d) {
        if (tl < nTiles) {
            const int e = min(tl * 16 + tc, E - 1);
            s = eidx[e]; d = eidx[E + e];
        } else { s = 0; d = 0; }
    };
    auto GATHER = [&](int s, int d, s16x8 (&xf)[4]) {
        const s16x8* ps = reinterpret_cast<const s16x8*>(hb + (size_t)s * EMB + bq * 8);
        const s16x8* pd = reinterpret_cast<const s16x8*>(hb + (size_t)d * EMB + bq * 8);
        xf[0] = ps[0]; xf[1] = ps[4];
        xf[2] = pd[0]; xf[3] = pd[4];
    };
    auto COMPUTE = [&](int tl, s16x8 (&xf)[4]) {
        f32x4 acc[8];
        #pragma unroll
        for (int mt = 0; mt < 8; ++mt) {
            acc[mt][0] = __uint_as_float(b1p[mt].x << 16);
            acc[mt][1] = __uint_as_float(b1p[mt].x & 0xffff0000u);
            acc[mt][2] = __uint_as_float(b1p[mt].y << 16);
            acc[mt][3] = __uint_as_float(b1p[mt].y & 0xffff0000u);
        }
        #pragma unroll
        for (int ks = 0; ks < 4; ++ks)
            #pragma unroll
            for (int nt = 0; nt < 8; ++nt)
                acc[nt] = __builtin_amdgcn_mfma_f32_16x16x32_bf16(
                              wf[(nt * 4 + ks) * 64], xf[ks], acc[nt], 0, 0, 0);

        s16x8 p[4];
        #pragma unroll
        for (int ks2 = 0; ks2 < 4; ++ks2)
            #pragma unroll
            for (int j = 0; j < 8; ++j) {
                const int mt = ks2 * 2 + (j >> 2), r = j & 3;
                p[ks2][j] = (short)f2bf(fmaxf(acc[mt][r], 0.f));
            }
        f32x4 o = {a20, a21, 0.f, 0.f};
        #pragma unroll
        for (int ks2 = 0; ks2 < 4; ++ks2)
            o = __builtin_amdgcn_mfma_f32_16x16x32_bf16(w2f[ks2], p[ks2], o, 0, 0, 0);

        if (lane < 16) {
            const int eo = tl * 16 + lane;
            if (eo < E)
                *reinterpret_cast<float2*>(out + (size_t)eo * 2) = make_float2(o[0], o[1]);
        }
    };

    // ---- depth-2 pipeline ----
    int sN, dN;
    LOADIDX(tile, sN, dN);
    s16x8 xC[4], xN[4];
    GATHER(sN, dN, xC);
    LOADIDX(tile + stride, sN, dN);

    while (true) {
        GATHER(sN, dN, xN);
        LOADIDX(tile + 2 * stride, sN, dN);
        COMPUTE(tile, xC);
        tile += stride;
        if (tile >= nTiles) break;

        GATHER(sN, dN, xC);
        LOADIDX(tile + 2 * stride, sN, dN);
        COMPUTE(tile, xN);
        tile += stride;
        if (tile >= nTiles) break;
    }
}

// ---- fallback (ws too small; correct but slow) ----
__global__ void edge_mlp_naive(const float* __restrict__ h, const int* __restrict__ eidx,
                               const float* __restrict__ W1, const float* __restrict__ b1,
                               const float* __restrict__ W2, const float* __restrict__ b2,
                               float* __restrict__ out, int E) {
    const int e = blockIdx.x * 256 + threadIdx.x;
    if (e >= E) return;
    const float* hs = h + (size_t)eidx[e] * EMB;
    const float* hd = h + (size_t)eidx[E + e] * EMB;
    float o0 = b2[0], o1 = b2[1];
    for (int j = 0; j < HID; ++j) {
        float a = b1[j];
        for (int k = 0; k < EMB; ++k)
            a += hs[k] * W1[(size_t)k * HID + j] + hd[k] * W1[(size_t)(k + EMB) * HID + j];
        a = fmaxf(a, 0.f);
        o0 = fmaf(a, W2[j * 2 + 0], o0);
        o1 = fmaf(a, W2[j * 2 + 1], o1);
    }
    out[(size_t)e * 2 + 0] = o0;
    out[(size_t)e * 2 + 1] = o1;
}

extern "C" void kernel_launch(void* const* d_in, const int* in_sizes, int n_in,
                              void* d_out, int out_size, void* d_ws, size_t ws_size,
                              hipStream_t stream)
{
    const float* h  = (const float*)d_in[0];
    const int*   ei = (const int*)d_in[1];
    const float* W1 = (const float*)d_in[2];
    const float* b1 = (const float*)d_in[3];
    const float* W2 = (const float*)d_in[4];
    const float* b2 = (const float*)d_in[5];
    float* out = (float*)d_out;

    const int nNodes = in_sizes[0] / EMB;
    const int E      = in_sizes[1] / 2;
    const int nTiles = (E + 15) / 16;

    const size_t hbElems = (size_t)nNodes * EMB;
    const size_t need    = hbElems * 2 + 16384 * 2;

    if (ws_size >= need) {
        unsigned short* hb  = (unsigned short*)d_ws;
        unsigned short* tab = hb + hbElems;
        const int n8 = (int)(hbElems / 8);
        hipLaunchKernelGGL(conv_h_kernel, dim3((n8 + 255) / 256), dim3(256), 0, stream,
                           h, hb, n8);
        hipLaunchKernelGGL(pack_w1, dim3(64), dim3(256), 0, stream, W1, tab);
        hipLaunchKernelGGL(edge_mlp_r6, dim3(1024), dim3(256), 0, stream,
                           hb, tab, ei, b1, W2, b2, out, E, nTiles);
    } else {
        hipLaunchKernelGGL(edge_mlp_naive, dim3((E + 255) / 256), dim3(256), 0, stream,
                           h, ei, W1, b1, W2, b2, out, E);
    }
}